// Round 3
// baseline (2479.355 us; speedup 1.0000x reference)
//
#include <hip/hip_runtime.h>
#include <math.h>

#define Hc   128
#define Bc   512
#define Tc   64
#define NXc  518
#define NCELL (518*518)
#define NEV  (Bc*Tc)            // 32768 events
#define SWc  2

// ---------------- precompute kernels ----------------

__global__ void k_build(const float* __restrict__ feat, int* __restrict__ head,
                        int* __restrict__ nxt, int* __restrict__ cellxy) {
    int gid = blockIdx.x * 256 + threadIdx.x;
    if (gid >= NEV) return;
    int b = gid >> 6, t = gid & 63;
    int base = (b * Tc + t) * 4;
    int gx = (int)feat[base + 2] + SWc;
    int gy = (int)feat[base + 3] + SWc;
    gx = min(max(gx, 0), NXc - 1);
    gy = min(max(gy, 0), NXc - 1);
    int cell = gx * NXc + gy;
    int e = t * Bc + b;
    cellxy[e] = (gx << 16) | gy;
    int old = atomicExch(&head[cell], e);
    nxt[e] = old;
}

__global__ void k_resolve(const int* __restrict__ head, const int* __restrict__ nxt,
                          const int* __restrict__ cellxy, int* __restrict__ dep) {
    int gid = blockIdx.x * 256 + threadIdx.x;
    if (gid >= NEV * 25) return;
    int r = gid / 25, k = gid - r * 25;
    int t = r & 63, b = r >> 6;
    int e0 = t * Bc + b;
    int xy = cellxy[e0];
    int gx = xy >> 16, gy = xy & 0xffff;
    int cx = gx + (k / 5) - SWc, cy = gy + (k % 5) - SWc;
    cx = min(max(cx, 0), NXc - 1);
    cy = min(max(cy, 0), NXc - 1);
    int cell = cx * NXc + cy;
    int best = -1;
    for (int e = head[cell]; e >= 0; e = nxt[e])
        if ((e >> 9) < t && e > best) best = e;
    dep[r * 25 + k] = best;
}

// ---------------- fast math (huge tolerance headroom) ----------------

#define LOG2E 1.4426950408889634f
__device__ __forceinline__ float fexp(float x)  { return __builtin_amdgcn_exp2f(x * LOG2E); }
__device__ __forceinline__ float fsig(float x)  { return __builtin_amdgcn_rcpf(1.f + fexp(-x)); }
__device__ __forceinline__ float ftanh(float x) { return 1.f - 2.f * __builtin_amdgcn_rcpf(1.f + fexp(2.f * x)); }

// ---------------- main persistent dataflow kernel ----------------

__global__ __launch_bounds__(512, 1)
void step_main(const float* __restrict__ feat, const float* __restrict__ Wih,
               const float* __restrict__ bih,  const float* __restrict__ Whh,
               const float* __restrict__ bhh,  const float* __restrict__ Wout,
               const float* __restrict__ bout, const int*   __restrict__ seq,
               const int*   __restrict__ dep,  float* __restrict__ vbuf,
               unsigned*    __restrict__ flags, float* __restrict__ dout) {
    __shared__ float hid[256];     // 2 chains * 128
    __shared__ float g[1024];      // 2 * 512 gate pre-acts; reused as cat[2][256]
    __shared__ float gin[256];
    __shared__ float qv[256], ug[256], sg[256], ctr[256];
    __shared__ float scor[64];     // 2 * 32
    __shared__ float pmix[1024];   // 2 chains * 4 waves * 128
    __shared__ float fxy[16];      // 2 parities * 8
    __shared__ int   depv[64];     // 2 * 25 (+pad)

    const int tid  = threadIdx.x;
    const int blk  = blockIdx.x;
    const int lane = tid & 63;
    const int w    = tid >> 6;          // wave 0..7
    const int wj   = w >> 2;            // chain of this wave
    const int ww   = w & 3;             // wave-within-chain

    // ---- persistent per-thread register weights ----
    // W_hh: one full row (128 f)
    const int o = tid;
    float4 wr[32];
    {
        const float4* wp = (const float4*)(Whh + (size_t)o * Hc);
        #pragma unroll
        for (int i = 0; i < 32; ++i) wr[i] = wp[i];
    }
    const float bihr = bih[o], bhhr = bhh[o];
    const float wih0 = Wih[o * 2 + 0], wih1 = Wih[o * 2 + 1];
    const int chunk = o >> 7;

    // W_out: quarter-row per thread. q = tid&3 (in-lane for shfl reduce),
    // oo = tid>>2 (0..127). Odd q read columns in reverse -> disjoint LDS banks.
    const int q   = tid & 3;
    const int oo  = tid >> 2;
    const int rev = q & 1;
    float4 wo[16];
    {
        const float* wbase = Wout + (size_t)oo * 256 + q * 64 + (rev ? 60 : 0);
        #pragma unroll
        for (int i = 0; i < 16; ++i)
            wo[i] = *(const float4*)(wbase + (rev ? -(4 * i) : 4 * i));
    }
    const float boutr = bout[oo];
    const int s0 = max(seq[blk * 2 + 0], 1) - 1;
    const int s1 = max(seq[blk * 2 + 1], 1) - 1;

    if (tid < 256) hid[tid] = 0.f;
    if (tid < 8) { int j = tid >> 2, c = tid & 3;
                   fxy[tid] = feat[((size_t)(blk * 2 + j) * Tc + 0) * 4 + c]; }
    __syncthreads();

    const float NEG_INF = -__builtin_inff();

    for (int t = 0; t < Tc; ++t) {
        const float* fx = fxy + (t & 1) * 8;

        // ---- P1: gh dots (W_hh regs, hid LDS broadcast); dep+fxy prefetch ----
        float accs[2];
        #pragma unroll
        for (int j = 0; j < 2; ++j) {
            const float4* hp = (const float4*)(hid + j * 128);
            float a0 = 0.f, a1 = 0.f, a2 = 0.f, a3 = 0.f;
            #pragma unroll
            for (int i = 0; i < 32; ++i) {
                float4 h4 = hp[i], w4 = wr[i];
                a0 = fmaf(w4.x, h4.x, a0); a1 = fmaf(w4.y, h4.y, a1);
                a2 = fmaf(w4.z, h4.z, a2); a3 = fmaf(w4.w, h4.w, a3);
            }
            accs[j] = (a0 + a1) + (a2 + a3);
        }
        #pragma unroll
        for (int j = 0; j < 2; ++j) {
            float gi  = fmaf(wih0, fx[j * 4 + 0], wih1 * fx[j * 4 + 1]);
            float val = accs[j] + bhhr + ((chunk == 2) ? 0.f : (gi + bihr));
            g[j * 512 + o] = val;
            if (chunk == 2) gin[j * 128 + (o & 127)] = gi + bihr;
        }
        if (tid < 50) {
            int j = (tid >= 25), k = tid - j * 25;
            depv[tid] = dep[(((size_t)(blk * 2 + j)) * Tc + t) * 25 + k];
        }
        if (tid >= 56 && tid < 64 && t + 1 < Tc) {
            int idx = tid - 56, j = idx >> 2, c = idx & 3;
            fxy[((t + 1) & 1) * 8 + idx] =
                feat[((size_t)(blk * 2 + j) * Tc + (t + 1)) * 4 + c];
        }
        __syncthreads();

        // ---- P2: gates (tid<256) + spin-wait (lane0/wave, backoff) ----
        if (tid < 256) {
            int j = tid >> 7, h = tid & 127;
            float gr = g[j * 512 + h],       gu = g[j * 512 + 128 + h];
            float gn = g[j * 512 + 256 + h], gs = g[j * 512 + 384 + h];
            float rr = fsig(gr), uu = fsig(gu), ss = fsig(gs);
            float nn = ftanh(gin[j * 128 + h] + rr * gn);
            qv[j * 128 + h] = nn; ug[j * 128 + h] = uu; sg[j * 128 + h] = ss;
            ctr[j * 128 + h] = 0.f;
        }
        if (lane == 0) {
            #pragma unroll
            for (int kk = 0; kk < 7; ++kk) {
                int k = ww + 4 * kk;
                if (k < 25) {
                    int e = depv[wj * 25 + k];
                    if (e >= 0) {
                        while (__hip_atomic_load(&flags[e], __ATOMIC_RELAXED,
                                                 __HIP_MEMORY_SCOPE_AGENT) == 0u)
                            __builtin_amdgcn_s_sleep(4);
                    }
                }
            }
        }
        __syncthreads();   // full fence: flag-gated vbuf now safe to read cached

        // ---- P4: gather (CACHED loads: write-once lines, flag-gated) ----
        const float q0 = qv[wj * 128 + 2 * lane];
        const float q1 = qv[wj * 128 + 2 * lane + 1];
        float2 valk[7];
        #pragma unroll
        for (int kk = 0; kk < 7; ++kk) {
            int k = ww + 4 * kk;
            valk[kk] = make_float2(0.f, 0.f);
            if (k < 25) {
                int e = depv[wj * 25 + k];
                float sc;
                if (e >= 0) {
                    float2 v = *(const float2*)(vbuf + (size_t)e * Hc + 2 * lane);
                    valk[kk] = v;
                    float d = fmaf(v.x, q0, v.y * q1);
                    #pragma unroll
                    for (int m = 1; m < 64; m <<= 1) d += __shfl_xor(d, m, 64);
                    sc = (d == 0.f) ? NEG_INF : d;
                    if (k == 12) { ctr[wj * 128 + 2 * lane]     = v.x;
                                   ctr[wj * 128 + 2 * lane + 1] = v.y; }
                } else sc = NEG_INF;
                if (lane == 0) scor[wj * 32 + k] = sc;
            }
        }
        __syncthreads();

        // ---- P56: redundant per-wave softmax (32-lane groups) + mix partials ----
        {
            int k2 = lane & 31;
            float v = (k2 < 25) ? scor[wj * 32 + k2] : NEG_INF;
            float m = v;
            #pragma unroll
            for (int mm = 1; mm < 32; mm <<= 1) m = fmaxf(m, __shfl_xor(m, mm, 64));
            float a = 0.f;
            if (m != NEG_INF) {
                float p = (v == NEG_INF) ? 0.f : fexp(v - m);
                float s = p;
                #pragma unroll
                for (int mm = 1; mm < 32; mm <<= 1) s += __shfl_xor(s, mm, 64);
                a = p / s;
            }
            float pm0 = 0.f, pm1 = 0.f;
            #pragma unroll
            for (int kk = 0; kk < 7; ++kk) {
                int k = ww + 4 * kk;
                if (k < 25) {
                    float ak = __shfl(a, k, 64);
                    pm0 = fmaf(ak, valk[kk].x, pm0);
                    pm1 = fmaf(ak, valk[kk].y, pm1);
                }
            }
            pmix[(wj * 4 + ww) * 128 + 2 * lane]     = pm0;
            pmix[(wj * 4 + ww) * 128 + 2 * lane + 1] = pm1;
        }
        __syncthreads();

        // ---- P7a: cat = [mix, q] into g ----
        if (tid < 256) {
            int j = tid >> 7, h = tid & 127;
            float mix = pmix[(j * 4 + 0) * 128 + h] + pmix[(j * 4 + 1) * 128 + h]
                      + pmix[(j * 4 + 2) * 128 + h] + pmix[(j * 4 + 3) * 128 + h];
            g[j * 512 + h] = mix;
            g[j * 512 + 128 + h] = qv[j * 128 + h];
        }
        __syncthreads();

        // ---- P7b: quarter dots (W_out in regs) + shfl reduce + epilogue ----
        {
            const float* gb = g + q * 64 + (rev ? 60 : 0);
            float acc0 = 0.f, acc1 = 0.f;
            #pragma unroll
            for (int i = 0; i < 16; ++i) {
                int offw = rev ? -(4 * i) : (4 * i);
                float4 wv = wo[i];
                float4 c0 = *(const float4*)(gb + offw);
                float4 c1 = *(const float4*)(gb + 512 + offw);
                acc0 = fmaf(wv.x, c0.x, fmaf(wv.y, c0.y, fmaf(wv.z, c0.z, fmaf(wv.w, c0.w, acc0))));
                acc1 = fmaf(wv.x, c1.x, fmaf(wv.y, c1.y, fmaf(wv.z, c1.z, fmaf(wv.w, c1.w, acc1))));
            }
            acc0 += __shfl_xor(acc0, 1, 64); acc0 += __shfl_xor(acc0, 2, 64);
            acc1 += __shfl_xor(acc1, 1, 64); acc1 += __shfl_xor(acc1, 2, 64);
            if (q < 2) {
                int j = q, h = oo;
                float tot = (q == 0) ? acc0 : acc1;
                float at  = ftanh(tot + boutr);
                float n  = qv[j * 128 + h], uu = ug[j * 128 + h];
                float ss = sg[j * 128 + h], hv = hid[j * 128 + h];
                float curr = fmaf(ss, at, n);
                float outv = curr + uu * (hv - curr);
                hid[j * 128 + h] = outv;
                float upd = fmaf(ss, ctr[j * 128 + h], (1.f - ss) * outv);
                __hip_atomic_store(&vbuf[((size_t)(t * Bc + blk * 2 + j)) * Hc + h],
                                   upd, __ATOMIC_RELAXED, __HIP_MEMORY_SCOPE_AGENT);
                int sj = (j == 0) ? s0 : s1;
                if (sj == t) dout[(size_t)(blk * 2 + j) * Hc + h] = outv;
            }
        }
        __syncthreads();   // drains vmcnt(0): vbuf stores device-visible
        if (tid == 0 || tid == 256) {
            int j = tid >> 8;
            __hip_atomic_store(&flags[t * Bc + blk * 2 + j], 1u,
                               __ATOMIC_RELAXED, __HIP_MEMORY_SCOPE_AGENT);
        }
    }
}

// ---------------- host launch ----------------

extern "C" void kernel_launch(void* const* d_in, const int* in_sizes, int n_in,
                              void* d_out, int out_size, void* d_ws, size_t ws_size,
                              hipStream_t stream) {
    const float* feat = (const float*)d_in[0];
    const float* Wih  = (const float*)d_in[1];
    const float* bih  = (const float*)d_in[2];
    const float* Whh  = (const float*)d_in[3];
    const float* bhh  = (const float*)d_in[4];
    const float* Wout = (const float*)d_in[5];
    const float* bout = (const float*)d_in[6];
    const int*   seq  = (const int*)d_in[7];

    char* ws = (char*)d_ws;
    size_t off = 0;
    auto carve = [&](size_t bytes) { char* p = ws + off; off += (bytes + 511) & ~(size_t)511; return p; };
    float*    vbuf   = (float*)   carve((size_t)NEV * Hc * 4);
    int*      head   = (int*)     carve((size_t)NCELL * 4);
    int*      nxt    = (int*)     carve((size_t)NEV * 4);
    int*      cellxy = (int*)     carve((size_t)NEV * 4);
    int*      dep    = (int*)     carve((size_t)NEV * 25 * 4);
    unsigned* flags  = (unsigned*)carve((size_t)NEV * 4);

    hipMemsetAsync(head, 0xFF, (size_t)NCELL * 4, stream);
    hipMemsetAsync(flags, 0, (size_t)NEV * 4, stream);

    k_build<<<(NEV + 255) / 256, 256, 0, stream>>>(feat, head, nxt, cellxy);
    k_resolve<<<(NEV * 25 + 255) / 256, 256, 0, stream>>>(head, nxt, cellxy, dep);

    step_main<<<256, 512, 0, stream>>>(feat, Wih, bih, Whh, bhh, Wout, bout,
                                       seq, dep, vbuf, flags, (float*)d_out);
}

// Round 4
// 2427.386 us; speedup vs baseline: 1.0214x; 1.0214x over previous
//
#include <hip/hip_runtime.h>
#include <math.h>

#define Hc   128
#define Bc   512
#define Tc   64
#define NXc  518
#define NCELL (518*518)
#define NEV  (Bc*Tc)            // 32768 events
#define SWc  2

// ---------------- precompute kernels ----------------

__global__ void k_build(const float* __restrict__ feat, int* __restrict__ head,
                        int* __restrict__ nxt, int* __restrict__ cellxy) {
    int gid = blockIdx.x * 256 + threadIdx.x;
    if (gid >= NEV) return;
    int b = gid >> 6, t = gid & 63;
    int base = (b * Tc + t) * 4;
    int gx = (int)feat[base + 2] + SWc;
    int gy = (int)feat[base + 3] + SWc;
    gx = min(max(gx, 0), NXc - 1);
    gy = min(max(gy, 0), NXc - 1);
    int cell = gx * NXc + gy;
    int e = t * Bc + b;
    cellxy[e] = (gx << 16) | gy;
    int old = atomicExch(&head[cell], e);
    nxt[e] = old;
}

__global__ void k_resolve(const int* __restrict__ head, const int* __restrict__ nxt,
                          const int* __restrict__ cellxy, int* __restrict__ dep) {
    int gid = blockIdx.x * 256 + threadIdx.x;
    if (gid >= NEV * 25) return;
    int r = gid / 25, k = gid - r * 25;
    int t = r & 63, b = r >> 6;
    int e0 = t * Bc + b;
    int xy = cellxy[e0];
    int gx = xy >> 16, gy = xy & 0xffff;
    int cx = gx + (k / 5) - SWc, cy = gy + (k % 5) - SWc;
    cx = min(max(cx, 0), NXc - 1);
    cy = min(max(cy, 0), NXc - 1);
    int cell = cx * NXc + cy;
    int best = -1;
    for (int e = head[cell]; e >= 0; e = nxt[e])
        if ((e >> 9) < t && e > best) best = e;
    dep[r * 25 + k] = best;
}

// ---------------- fast math ----------------

#define LOG2E 1.4426950408889634f
__device__ __forceinline__ float fexp(float x)  { return __builtin_amdgcn_exp2f(x * LOG2E); }
__device__ __forceinline__ float fsig(float x)  { return __builtin_amdgcn_rcpf(1.f + fexp(-x)); }
__device__ __forceinline__ float ftanh(float x) { return 1.f - 2.f * __builtin_amdgcn_rcpf(1.f + fexp(2.f * x)); }

// ---------------- main persistent dataflow kernel ----------------

__global__ void
__launch_bounds__(512, 2)
__attribute__((amdgpu_waves_per_eu(2, 2)))   // pin allocator to 2 waves/EU -> full 256-VGPR budget, no spill
step_main(const float* __restrict__ feat, const float* __restrict__ Wih,
          const float* __restrict__ bih,  const float* __restrict__ Whh,
          const float* __restrict__ bhh,  const float* __restrict__ Wout,
          const float* __restrict__ bout, const int*   __restrict__ seq,
          const int*   __restrict__ dep,  float* __restrict__ vbuf,
          unsigned*    __restrict__ flags, float* __restrict__ dout) {
    __shared__ float hid[256];     // 2 chains * 128
    __shared__ float g[1024];      // 2 * 512 gate pre-acts; reused as cat[2][256]
    __shared__ float gin[256];
    __shared__ float qv[256], ug[256], sg[256], ctr[256];
    __shared__ float scor[64];     // 2 * 32
    __shared__ float pmix[1024];   // 2 chains * 4 waves * 128
    __shared__ float fxy[16];      // 2 parities * 8
    __shared__ int   depv[64];     // 2 * 25 (+pad)

    const int tid  = threadIdx.x;
    const int blk  = blockIdx.x;
    const int lane = tid & 63;
    const int w    = tid >> 6;          // wave 0..7
    const int wj   = w >> 2;            // chain of this wave
    const int ww   = w & 3;             // wave-within-chain

    // ---- persistent register weights ----
    const int o = tid;
    float4 wr[32];                      // full W_hh row: 128 VGPRs
    {
        const float4* wp = (const float4*)(Whh + (size_t)o * Hc);
        #pragma unroll
        for (int i = 0; i < 32; ++i) wr[i] = wp[i];
    }
    const float bihr = bih[o], bhhr = bhh[o];
    const float wih0 = Wih[o * 2 + 0], wih1 = Wih[o * 2 + 1];
    const int chunk = o >> 7;

    // W_out quarter-row per thread: 64 VGPRs. Odd q reversed for LDS bank stagger.
    const int q   = tid & 3;
    const int oo  = tid >> 2;
    const int rev = q & 1;
    float4 wo[16];
    {
        const float* wbase = Wout + (size_t)oo * 256 + q * 64 + (rev ? 60 : 0);
        #pragma unroll
        for (int i = 0; i < 16; ++i)
            wo[i] = *(const float4*)(wbase + (rev ? -(4 * i) : 4 * i));
    }
    const float boutr = bout[oo];
    const int s0 = max(seq[blk * 2 + 0], 1) - 1;
    const int s1 = max(seq[blk * 2 + 1], 1) - 1;

    if (tid < 256) hid[tid] = 0.f;
    if (tid < 8) { int j = tid >> 2, c = tid & 3;
                   fxy[tid] = feat[((size_t)(blk * 2 + j) * Tc + 0) * 4 + c]; }
    __syncthreads();

    const float NEG_INF = -__builtin_inff();

    for (int t = 0; t < Tc; ++t) {
        const float* fx = fxy + (t & 1) * 8;

        // ---- P1: gh dots (W_hh regs, hid LDS broadcast); dep+fxy prefetch ----
        float accs[2];
        #pragma unroll
        for (int j = 0; j < 2; ++j) {
            const float4* hp = (const float4*)(hid + j * 128);
            float a0 = 0.f, a1 = 0.f, a2 = 0.f, a3 = 0.f;
            #pragma unroll
            for (int i = 0; i < 32; ++i) {
                float4 h4 = hp[i], w4 = wr[i];
                a0 = fmaf(w4.x, h4.x, a0); a1 = fmaf(w4.y, h4.y, a1);
                a2 = fmaf(w4.z, h4.z, a2); a3 = fmaf(w4.w, h4.w, a3);
            }
            accs[j] = (a0 + a1) + (a2 + a3);
        }
        #pragma unroll
        for (int j = 0; j < 2; ++j) {
            float gi  = fmaf(wih0, fx[j * 4 + 0], wih1 * fx[j * 4 + 1]);
            float val = accs[j] + bhhr + ((chunk == 2) ? 0.f : (gi + bihr));
            g[j * 512 + o] = val;
            if (chunk == 2) gin[j * 128 + (o & 127)] = gi + bihr;
        }
        if (tid < 50) {
            int j = (tid >= 25), k = tid - j * 25;
            depv[tid] = dep[(((size_t)(blk * 2 + j)) * Tc + t) * 25 + k];
        }
        if (tid >= 56 && tid < 64 && t + 1 < Tc) {
            int idx = tid - 56, j = idx >> 2, c = idx & 3;
            fxy[((t + 1) & 1) * 8 + idx] =
                feat[((size_t)(blk * 2 + j) * Tc + (t + 1)) * 4 + c];
        }
        __syncthreads();

        // ---- P2: gates (tid<256) + wave-parallel spin (1 dep per lane) ----
        if (tid < 256) {
            int j = tid >> 7, h = tid & 127;
            float gr = g[j * 512 + h],       gu = g[j * 512 + 128 + h];
            float gn = g[j * 512 + 256 + h], gs = g[j * 512 + 384 + h];
            float rr = fsig(gr), uu = fsig(gu), ss = fsig(gs);
            float nn = ftanh(gin[j * 128 + h] + rr * gn);
            qv[j * 128 + h] = nn; ug[j * 128 + h] = uu; sg[j * 128 + h] = ss;
            ctr[j * 128 + h] = 0.f;
        }
        {
            int e = (lane < 25) ? depv[wj * 25 + lane] : -1;
            bool pend = (e >= 0);
            if (pend && __hip_atomic_load(&flags[e], __ATOMIC_RELAXED,
                                          __HIP_MEMORY_SCOPE_AGENT) != 0u)
                pend = false;
            while (__any(pend)) {
                __builtin_amdgcn_s_sleep(1);
                if (pend && __hip_atomic_load(&flags[e], __ATOMIC_RELAXED,
                                              __HIP_MEMORY_SCOPE_AGENT) != 0u)
                    pend = false;
            }
            asm volatile("" ::: "memory");   // keep vbuf loads after the spin
        }
        __syncthreads();

        // ---- P4: gather (cached; flag-gated write-once lines) + scores ----
        const float q0 = qv[wj * 128 + 2 * lane];
        const float q1 = qv[wj * 128 + 2 * lane + 1];
        #pragma unroll
        for (int kk = 0; kk < 7; ++kk) {
            int k = ww + 4 * kk;
            if (k < 25) {
                int e = depv[wj * 25 + k];
                float sc;
                if (e >= 0) {
                    float2 v = *(const float2*)(vbuf + (size_t)e * Hc + 2 * lane);
                    float d = fmaf(v.x, q0, v.y * q1);
                    #pragma unroll
                    for (int m = 1; m < 64; m <<= 1) d += __shfl_xor(d, m, 64);
                    sc = (d == 0.f) ? NEG_INF : d;
                    if (k == 12) { ctr[wj * 128 + 2 * lane]     = v.x;
                                   ctr[wj * 128 + 2 * lane + 1] = v.y; }
                } else sc = NEG_INF;
                if (lane == 0) scor[wj * 32 + k] = sc;
            }
        }
        __syncthreads();

        // ---- P56: redundant per-wave softmax + mix partials (re-read L1-hot vbuf) ----
        {
            int k2 = lane & 31;
            float v = (k2 < 25) ? scor[wj * 32 + k2] : NEG_INF;
            float m = v;
            #pragma unroll
            for (int mm = 1; mm < 32; mm <<= 1) m = fmaxf(m, __shfl_xor(m, mm, 64));
            float a = 0.f;
            if (m != NEG_INF) {
                float p = (v == NEG_INF) ? 0.f : fexp(v - m);
                float s = p;
                #pragma unroll
                for (int mm = 1; mm < 32; mm <<= 1) s += __shfl_xor(s, mm, 64);
                a = p / s;
            }
            float pm0 = 0.f, pm1 = 0.f;
            #pragma unroll
            for (int kk = 0; kk < 7; ++kk) {
                int k = ww + 4 * kk;
                if (k < 25) {
                    int e = depv[wj * 25 + k];
                    if (e >= 0) {
                        float ak = __shfl(a, k, 64);
                        float2 v = *(const float2*)(vbuf + (size_t)e * Hc + 2 * lane);
                        pm0 = fmaf(ak, v.x, pm0);
                        pm1 = fmaf(ak, v.y, pm1);
                    }
                }
            }
            pmix[(wj * 4 + ww) * 128 + 2 * lane]     = pm0;
            pmix[(wj * 4 + ww) * 128 + 2 * lane + 1] = pm1;
        }
        __syncthreads();

        // ---- P7a: cat = [mix, q] into g ----
        if (tid < 256) {
            int j = tid >> 7, h = tid & 127;
            float mix = pmix[(j * 4 + 0) * 128 + h] + pmix[(j * 4 + 1) * 128 + h]
                      + pmix[(j * 4 + 2) * 128 + h] + pmix[(j * 4 + 3) * 128 + h];
            g[j * 512 + h] = mix;
            g[j * 512 + 128 + h] = qv[j * 128 + h];
        }
        __syncthreads();

        // ---- P7b: quarter dots (W_out regs) + shfl reduce + epilogue ----
        {
            const float* gb = g + q * 64 + (rev ? 60 : 0);
            float acc0 = 0.f, acc1 = 0.f;
            #pragma unroll
            for (int i = 0; i < 16; ++i) {
                int offw = rev ? -(4 * i) : (4 * i);
                float4 wv = wo[i];
                float4 c0 = *(const float4*)(gb + offw);
                float4 c1 = *(const float4*)(gb + 512 + offw);
                acc0 = fmaf(wv.x, c0.x, fmaf(wv.y, c0.y, fmaf(wv.z, c0.z, fmaf(wv.w, c0.w, acc0))));
                acc1 = fmaf(wv.x, c1.x, fmaf(wv.y, c1.y, fmaf(wv.z, c1.z, fmaf(wv.w, c1.w, acc1))));
            }
            acc0 += __shfl_xor(acc0, 1, 64); acc0 += __shfl_xor(acc0, 2, 64);
            acc1 += __shfl_xor(acc1, 1, 64); acc1 += __shfl_xor(acc1, 2, 64);
            if (q < 2) {
                int j = q, h = oo;
                float tot = (q == 0) ? acc0 : acc1;
                float at  = ftanh(tot + boutr);
                float n  = qv[j * 128 + h], uu = ug[j * 128 + h];
                float ss = sg[j * 128 + h], hv = hid[j * 128 + h];
                float curr = fmaf(ss, at, n);
                float outv = curr + uu * (hv - curr);
                hid[j * 128 + h] = outv;
                float upd = fmaf(ss, ctr[j * 128 + h], (1.f - ss) * outv);
                __hip_atomic_store(&vbuf[((size_t)(t * Bc + blk * 2 + j)) * Hc + h],
                                   upd, __ATOMIC_RELAXED, __HIP_MEMORY_SCOPE_AGENT);
                int sj = (j == 0) ? s0 : s1;
                if (sj == t) dout[(size_t)(blk * 2 + j) * Hc + h] = outv;
            }
        }
        __syncthreads();   // drains vmcnt(0): vbuf stores device-visible
        if (tid == 0 || tid == 256) {
            int j = tid >> 8;
            __hip_atomic_store(&flags[t * Bc + blk * 2 + j], 1u,
                               __ATOMIC_RELAXED, __HIP_MEMORY_SCOPE_AGENT);
        }
    }
}

// ---------------- host launch ----------------

extern "C" void kernel_launch(void* const* d_in, const int* in_sizes, int n_in,
                              void* d_out, int out_size, void* d_ws, size_t ws_size,
                              hipStream_t stream) {
    const float* feat = (const float*)d_in[0];
    const float* Wih  = (const float*)d_in[1];
    const float* bih  = (const float*)d_in[2];
    const float* Whh  = (const float*)d_in[3];
    const float* bhh  = (const float*)d_in[4];
    const float* Wout = (const float*)d_in[5];
    const float* bout = (const float*)d_in[6];
    const int*   seq  = (const int*)d_in[7];

    char* ws = (char*)d_ws;
    size_t off = 0;
    auto carve = [&](size_t bytes) { char* p = ws + off; off += (bytes + 511) & ~(size_t)511; return p; };
    float*    vbuf   = (float*)   carve((size_t)NEV * Hc * 4);
    int*      head   = (int*)     carve((size_t)NCELL * 4);
    int*      nxt    = (int*)     carve((size_t)NEV * 4);
    int*      cellxy = (int*)     carve((size_t)NEV * 4);
    int*      dep    = (int*)     carve((size_t)NEV * 25 * 4);
    unsigned* flags  = (unsigned*)carve((size_t)NEV * 4);

    hipMemsetAsync(head, 0xFF, (size_t)NCELL * 4, stream);
    hipMemsetAsync(flags, 0, (size_t)NEV * 4, stream);

    k_build<<<(NEV + 255) / 256, 256, 0, stream>>>(feat, head, nxt, cellxy);
    k_resolve<<<(NEV * 25 + 255) / 256, 256, 0, stream>>>(head, nxt, cellxy, dep);

    step_main<<<256, 512, 0, stream>>>(feat, Wih, bih, Whh, bhh, Wout, bout,
                                       seq, dep, vbuf, flags, (float*)d_out);
}

// Round 5
// 1267.701 us; speedup vs baseline: 1.9558x; 1.9148x over previous
//
#include <hip/hip_runtime.h>
#include <math.h>

#define Hc   128
#define Bc   512
#define Tc   64
#define NXc  518
#define NCELL (518*518)
#define NEV  (Bc*Tc)            // 32768 events
#define SWc  2

// ---------------- precompute kernels ----------------

__global__ void k_build(const float* __restrict__ feat, int* __restrict__ head,
                        int* __restrict__ nxt, int* __restrict__ cellxy) {
    int gid = blockIdx.x * 256 + threadIdx.x;
    if (gid >= NEV) return;
    int b = gid >> 6, t = gid & 63;
    int base = (b * Tc + t) * 4;
    int gx = (int)feat[base + 2] + SWc;
    int gy = (int)feat[base + 3] + SWc;
    gx = min(max(gx, 0), NXc - 1);
    gy = min(max(gy, 0), NXc - 1);
    int cell = gx * NXc + gy;
    int e = t * Bc + b;
    cellxy[e] = (gx << 16) | gy;
    int old = atomicExch(&head[cell], e);
    nxt[e] = old;
}

__global__ void k_resolve(const int* __restrict__ head, const int* __restrict__ nxt,
                          const int* __restrict__ cellxy, int* __restrict__ dep) {
    int gid = blockIdx.x * 256 + threadIdx.x;
    if (gid >= NEV * 25) return;
    int r = gid / 25, k = gid - r * 25;
    int t = r & 63, b = r >> 6;
    int e0 = t * Bc + b;
    int xy = cellxy[e0];
    int gx = xy >> 16, gy = xy & 0xffff;
    int cx = gx + (k / 5) - SWc, cy = gy + (k % 5) - SWc;
    cx = min(max(cx, 0), NXc - 1);
    cy = min(max(cy, 0), NXc - 1);
    int cell = cx * NXc + cy;
    int best = -1;
    for (int e = head[cell]; e >= 0; e = nxt[e])
        if ((e >> 9) < t && e > best) best = e;
    dep[r * 25 + k] = best;
}

// ---------------- fast math ----------------

#define LOG2E 1.4426950408889634f
__device__ __forceinline__ float fexp(float x)  { return __builtin_amdgcn_exp2f(x * LOG2E); }
__device__ __forceinline__ float fsig(float x)  { return __builtin_amdgcn_rcpf(1.f + fexp(-x)); }
__device__ __forceinline__ float ftanh(float x) { return 1.f - 2.f * __builtin_amdgcn_rcpf(1.f + fexp(2.f * x)); }

// ---------------- main persistent dataflow kernel ----------------

// LDS carve (floats). WoutL stride 260 (1040 B: 16B-aligned, 260%32=4).
#define WSTRIDE 260
#define L_WOUT  (128 * WSTRIDE)
constexpr int LDS_FLOATS = L_WOUT + 256 + 1024 + 256 + 256 + 256 + 256 + 256 + 64 + 2048 + 16 + 128 + 64;
constexpr int LDS_BYTES  = LDS_FLOATS * 4;   // 152,640 B <= 160 KiB

__global__ __launch_bounds__(1024, 4)
void step_main(const float* __restrict__ feat, const float* __restrict__ Wih,
               const float* __restrict__ bih,  const float* __restrict__ Whh,
               const float* __restrict__ bhh,  const float* __restrict__ Wout,
               const float* __restrict__ bout, const int*   __restrict__ seq,
               const int*   __restrict__ dep,  float* __restrict__ vbuf,
               unsigned*    __restrict__ flags, float* __restrict__ dout) {
    extern __shared__ float lds[];
    float* WoutL = lds;                 // 128*260
    float* hid   = WoutL + L_WOUT;      // 2*128
    float* g     = hid   + 256;         // 2*512 gate pre-acts; reused as cat[2][256]
    float* gin   = g     + 1024;        // 2*128
    float* qv    = gin   + 256;
    float* ug    = qv    + 256;
    float* sg    = ug    + 256;
    float* ctr   = sg    + 256;
    float* scor  = ctr   + 256;         // 2*32
    float* pmix  = scor  + 64;          // 16 rows * 128 (mix partials; reused as Wout partials)
    float* fxy   = pmix  + 2048;        // 2 parities * 8
    float* boutL = fxy   + 16;          // 128
    int*   depv  = (int*)(boutL + 128); // 2*25 (+pad)

    const int tid  = threadIdx.x;       // 0..1023
    const int blk  = blockIdx.x;
    const int lane = tid & 63;
    const int w    = tid >> 6;          // wave 0..15
    const int wj   = w >> 3;            // chain of this wave
    const int ww   = w & 7;             // wave-within-chain (8 per chain)

    // ---- persistent register weights: HALF a W_hh row per thread (64 VGPRs) ----
    const int o    = tid >> 1;          // row 0..511
    const int half = tid & 1;           // which 64-col half
    float4 wr[16];
    {
        const float4* wp = (const float4*)(Whh + (size_t)o * Hc + half * 64);
        #pragma unroll
        for (int i = 0; i < 16; ++i) wr[i] = wp[i];
    }
    const float bihr = bih[o], bhhr = bhh[o];
    const float wih0 = Wih[o * 2 + 0], wih1 = Wih[o * 2 + 1];
    const int chunk = o >> 7;

    // stage W_out (stride-260) + b_out into LDS
    for (int i = tid; i < 128 * 256; i += 1024)
        WoutL[(i >> 8) * WSTRIDE + (i & 255)] = Wout[i];
    if (tid < 128) boutL[tid] = bout[tid];
    if (tid < 256) hid[tid] = 0.f;
    if (tid < 8) { int j = tid >> 2, c = tid & 3;
                   fxy[tid] = feat[((size_t)(blk * 2 + j) * Tc + 0) * 4 + c]; }
    const int s0 = max(seq[blk * 2 + 0], 1) - 1;
    const int s1 = max(seq[blk * 2 + 1], 1) - 1;
    __syncthreads();

    const float NEG_INF = -__builtin_inff();

    for (int t = 0; t < Tc; ++t) {
        const float* fx = fxy + (t & 1) * 8;

        // ---- P1: half-row gh dots + pair-combine; dep + fxy prefetch ----
        float accs[2];
        #pragma unroll
        for (int j = 0; j < 2; ++j) {
            const float4* hp = (const float4*)(hid + j * 128 + half * 64);
            float a0 = 0.f, a1 = 0.f, a2 = 0.f, a3 = 0.f;
            #pragma unroll 4
            for (int i = 0; i < 16; ++i) {
                float4 h4 = hp[i], w4 = wr[i];
                a0 = fmaf(w4.x, h4.x, a0); a1 = fmaf(w4.y, h4.y, a1);
                a2 = fmaf(w4.z, h4.z, a2); a3 = fmaf(w4.w, h4.w, a3);
            }
            accs[j] = (a0 + a1) + (a2 + a3);
        }
        accs[0] += __shfl_xor(accs[0], 1, 64);
        accs[1] += __shfl_xor(accs[1], 1, 64);
        if (half == 0) {
            #pragma unroll
            for (int j = 0; j < 2; ++j) {
                float gi  = fmaf(wih0, fx[j * 4 + 0], wih1 * fx[j * 4 + 1]);
                float val = accs[j] + bhhr + ((chunk == 2) ? 0.f : (gi + bihr));
                g[j * 512 + o] = val;
                if (chunk == 2) gin[j * 128 + (o & 127)] = gi + bihr;
            }
        }
        if (tid < 50) {
            int j = (tid >= 25), k = tid - j * 25;
            depv[tid] = dep[(((size_t)(blk * 2 + j)) * Tc + t) * 25 + k];
        }
        if (tid >= 56 && tid < 64 && t + 1 < Tc) {
            int idx = tid - 56, j = idx >> 2, c = idx & 3;
            fxy[((t + 1) & 1) * 8 + idx] =
                feat[((size_t)(blk * 2 + j) * Tc + (t + 1)) * 4 + c];
        }
        __syncthreads();

        // ---- P2: gates (tid<256) + wave-parallel spin (1 dep per lane) ----
        if (tid < 256) {
            int j = tid >> 7, h = tid & 127;
            float gr = g[j * 512 + h],       gu = g[j * 512 + 128 + h];
            float gn = g[j * 512 + 256 + h], gs = g[j * 512 + 384 + h];
            float rr = fsig(gr), uu = fsig(gu), ss = fsig(gs);
            float nn = ftanh(gin[j * 128 + h] + rr * gn);
            qv[j * 128 + h] = nn; ug[j * 128 + h] = uu; sg[j * 128 + h] = ss;
            ctr[j * 128 + h] = 0.f;
        }
        {
            int e = (lane < 25) ? depv[wj * 25 + lane] : -1;
            bool pend = (e >= 0);
            if (pend && __hip_atomic_load(&flags[e], __ATOMIC_RELAXED,
                                          __HIP_MEMORY_SCOPE_AGENT) != 0u)
                pend = false;
            while (__any(pend)) {
                __builtin_amdgcn_s_sleep(1);
                if (pend && __hip_atomic_load(&flags[e], __ATOMIC_RELAXED,
                                              __HIP_MEMORY_SCOPE_AGENT) != 0u)
                    pend = false;
            }
            asm volatile("" ::: "memory");   // keep vbuf loads after the spin
        }
        __syncthreads();

        // ---- P4: gather (cached; flag-gated write-once lines) + scores ----
        const float q0 = qv[wj * 128 + 2 * lane];
        const float q1 = qv[wj * 128 + 2 * lane + 1];
        #pragma unroll
        for (int kk = 0; kk < 4; ++kk) {
            int k = ww + 8 * kk;
            if (k < 25) {
                int e = depv[wj * 25 + k];
                float sc;
                if (e >= 0) {
                    float2 v = *(const float2*)(vbuf + (size_t)e * Hc + 2 * lane);
                    float d = fmaf(v.x, q0, v.y * q1);
                    #pragma unroll
                    for (int m = 1; m < 64; m <<= 1) d += __shfl_xor(d, m, 64);
                    sc = (d == 0.f) ? NEG_INF : d;
                    if (k == 12) { ctr[wj * 128 + 2 * lane]     = v.x;
                                   ctr[wj * 128 + 2 * lane + 1] = v.y; }
                } else sc = NEG_INF;
                if (lane == 0) scor[wj * 32 + k] = sc;
            }
        }
        __syncthreads();

        // ---- P56: per-wave softmax + mix partials (vbuf re-read L1-hot) ----
        {
            int k2 = lane & 31;
            float v = (k2 < 25) ? scor[wj * 32 + k2] : NEG_INF;
            float m = v;
            #pragma unroll
            for (int mm = 1; mm < 32; mm <<= 1) m = fmaxf(m, __shfl_xor(m, mm, 64));
            float a = 0.f;
            if (m != NEG_INF) {
                float p = (v == NEG_INF) ? 0.f : fexp(v - m);
                float s = p;
                #pragma unroll
                for (int mm = 1; mm < 32; mm <<= 1) s += __shfl_xor(s, mm, 64);
                a = p / s;
            }
            float pm0 = 0.f, pm1 = 0.f;
            #pragma unroll
            for (int kk = 0; kk < 4; ++kk) {
                int k = ww + 8 * kk;
                if (k < 25) {
                    int e = depv[wj * 25 + k];
                    if (e >= 0) {
                        float ak = __shfl(a, k, 64);
                        float2 v = *(const float2*)(vbuf + (size_t)e * Hc + 2 * lane);
                        pm0 = fmaf(ak, v.x, pm0);
                        pm1 = fmaf(ak, v.y, pm1);
                    }
                }
            }
            *(float2*)&pmix[(wj * 8 + ww) * 128 + 2 * lane] = make_float2(pm0, pm1);
        }
        __syncthreads();

        // ---- P7a: cat = [mix, q] into g ----
        if (tid < 256) {
            int j = tid >> 7, h = tid & 127;
            float mix = 0.f;
            #pragma unroll
            for (int p = 0; p < 8; ++p) mix += pmix[(j * 8 + p) * 128 + h];
            g[j * 512 + h] = mix;
            g[j * 512 + 128 + h] = qv[j * 128 + h];
        }
        __syncthreads();

        // ---- P7b: W_out partial dots (8-way column split, LDS weights) ----
        {
            int oo = tid & 127, rep = tid >> 7;     // rep: 32-col slice
            const float4* wrow4 = (const float4*)(WoutL + oo * WSTRIDE + rep * 32);
            const float4* c04   = (const float4*)(g + rep * 32);
            const float4* c14   = (const float4*)(g + 512 + rep * 32);
            float acc0 = 0.f, acc1 = 0.f;
            #pragma unroll
            for (int i = 0; i < 8; ++i) {
                float4 wv = wrow4[i];
                float4 c0 = c04[i], c1 = c14[i];
                acc0 = fmaf(wv.x, c0.x, fmaf(wv.y, c0.y, fmaf(wv.z, c0.z, fmaf(wv.w, c0.w, acc0))));
                acc1 = fmaf(wv.x, c1.x, fmaf(wv.y, c1.y, fmaf(wv.z, c1.z, fmaf(wv.w, c1.w, acc1))));
            }
            pmix[rep * 128 + oo]       = acc0;     // chain 0 partials: rows 0..7
            pmix[(8 + rep) * 128 + oo] = acc1;     // chain 1 partials: rows 8..15
        }
        __syncthreads();

        // ---- P7c: combine + epilogue + vbuf/dout stores ----
        if (tid < 256) {
            int j = tid >> 7, h = tid & 127;
            float tot = boutL[h];
            #pragma unroll
            for (int p = 0; p < 8; ++p) tot += pmix[(j * 8 + p) * 128 + h];
            float at = ftanh(tot);
            float n  = qv[j * 128 + h], uu = ug[j * 128 + h];
            float ss = sg[j * 128 + h], hv = hid[j * 128 + h];
            float curr = fmaf(ss, at, n);
            float outv = curr + uu * (hv - curr);
            hid[j * 128 + h] = outv;
            float upd = fmaf(ss, ctr[j * 128 + h], (1.f - ss) * outv);
            __hip_atomic_store(&vbuf[((size_t)(t * Bc + blk * 2 + j)) * Hc + h],
                               upd, __ATOMIC_RELAXED, __HIP_MEMORY_SCOPE_AGENT);
            int sj = (j == 0) ? s0 : s1;
            if (sj == t) dout[(size_t)(blk * 2 + j) * Hc + h] = outv;
        }
        __syncthreads();   // drains vmcnt(0): vbuf stores device-visible
        if (tid == 0 || tid == 128) {
            int j = tid >> 7;
            __hip_atomic_store(&flags[t * Bc + blk * 2 + j], 1u,
                               __ATOMIC_RELAXED, __HIP_MEMORY_SCOPE_AGENT);
        }
    }
}

// ---------------- host launch ----------------

extern "C" void kernel_launch(void* const* d_in, const int* in_sizes, int n_in,
                              void* d_out, int out_size, void* d_ws, size_t ws_size,
                              hipStream_t stream) {
    const float* feat = (const float*)d_in[0];
    const float* Wih  = (const float*)d_in[1];
    const float* bih  = (const float*)d_in[2];
    const float* Whh  = (const float*)d_in[3];
    const float* bhh  = (const float*)d_in[4];
    const float* Wout = (const float*)d_in[5];
    const float* bout = (const float*)d_in[6];
    const int*   seq  = (const int*)d_in[7];

    char* ws = (char*)d_ws;
    size_t off = 0;
    auto carve = [&](size_t bytes) { char* p = ws + off; off += (bytes + 511) & ~(size_t)511; return p; };
    float*    vbuf   = (float*)   carve((size_t)NEV * Hc * 4);
    int*      head   = (int*)     carve((size_t)NCELL * 4);
    int*      nxt    = (int*)     carve((size_t)NEV * 4);
    int*      cellxy = (int*)     carve((size_t)NEV * 4);
    int*      dep    = (int*)     carve((size_t)NEV * 25 * 4);
    unsigned* flags  = (unsigned*)carve((size_t)NEV * 4);

    hipMemsetAsync(head, 0xFF, (size_t)NCELL * 4, stream);
    hipMemsetAsync(flags, 0, (size_t)NEV * 4, stream);

    k_build<<<(NEV + 255) / 256, 256, 0, stream>>>(feat, head, nxt, cellxy);
    k_resolve<<<(NEV * 25 + 255) / 256, 256, 0, stream>>>(head, nxt, cellxy, dep);

    hipFuncSetAttribute((const void*)step_main,
                        hipFuncAttributeMaxDynamicSharedMemorySize, LDS_BYTES);
    step_main<<<256, 1024, LDS_BYTES, stream>>>(feat, Wih, bih, Whh, bhh, Wout, bout,
                                                seq, dep, vbuf, flags, (float*)d_out);
}

// Round 6
// 538.221 us; speedup vs baseline: 4.6066x; 2.3554x over previous
//
#include <hip/hip_runtime.h>
#include <math.h>

#define Hc   128
#define Bc   512
#define Tc   64
#define NXc  518
#define NCELL (518*518)
#define NEV  (Bc*Tc)            // 32768 events
#define SWc  2

// ---------------- precompute kernels ----------------

__global__ void k_build(const float* __restrict__ feat, int* __restrict__ head,
                        int* __restrict__ nxt, int* __restrict__ cellxy) {
    int gid = blockIdx.x * 256 + threadIdx.x;
    if (gid >= NEV) return;
    int b = gid >> 6, t = gid & 63;
    int base = (b * Tc + t) * 4;
    int gx = (int)feat[base + 2] + SWc;
    int gy = (int)feat[base + 3] + SWc;
    gx = min(max(gx, 0), NXc - 1);
    gy = min(max(gy, 0), NXc - 1);
    int cell = gx * NXc + gy;
    int e = t * Bc + b;
    cellxy[e] = (gx << 16) | gy;
    int old = atomicExch(&head[cell], e);
    nxt[e] = old;
}

__global__ void k_resolve(const int* __restrict__ head, const int* __restrict__ nxt,
                          const int* __restrict__ cellxy, int* __restrict__ dep) {
    int gid = blockIdx.x * 256 + threadIdx.x;
    if (gid >= NEV * 25) return;
    int r = gid / 25, k = gid - r * 25;
    int t = r & 63, b = r >> 6;
    int e0 = t * Bc + b;
    int xy = cellxy[e0];
    int gx = xy >> 16, gy = xy & 0xffff;
    int cx = gx + (k / 5) - SWc, cy = gy + (k % 5) - SWc;
    cx = min(max(cx, 0), NXc - 1);
    cy = min(max(cy, 0), NXc - 1);
    int cell = cx * NXc + cy;
    int best = -1;
    for (int e = head[cell]; e >= 0; e = nxt[e])
        if ((e >> 9) < t && e > best) best = e;
    dep[r * 25 + k] = best;
}

// ---------------- fast math ----------------

#define LOG2E 1.4426950408889634f
__device__ __forceinline__ float fexp(float x)  { return __builtin_amdgcn_exp2f(x * LOG2E); }
__device__ __forceinline__ float fsig(float x)  { return __builtin_amdgcn_rcpf(1.f + fexp(-x)); }
__device__ __forceinline__ float ftanh(float x) { return 1.f - 2.f * __builtin_amdgcn_rcpf(1.f + fexp(2.f * x)); }

// ---------------- main persistent dataflow kernel ----------------

// W_out LDS stride 257 floats: (oo*257 + c) % 32 = (oo + c) % 32 -> 64-lane
// scalar read = clean 2-way aliasing (free, m136). Proven low-conflict in R1.
#define WSTRIDE 257
#define L_WOUT  (128 * WSTRIDE)
constexpr int LDS_FLOATS = L_WOUT + 256 + 1024 + 256 + 256 + 256 + 256 + 256 + 64 + 2048 + 16 + 128 + 64;
constexpr int LDS_BYTES  = LDS_FLOATS * 4;   // ~151 KB <= 160 KiB

__global__ void
__attribute__((amdgpu_flat_work_group_size(1024, 1024)))
__attribute__((amdgpu_waves_per_eu(4, 4)))   // exactly 4 waves/EU -> 128-VGPR budget, no occupancy-driven spill
step_main(const float* __restrict__ feat, const float* __restrict__ Wih,
          const float* __restrict__ bih,  const float* __restrict__ Whh,
          const float* __restrict__ bhh,  const float* __restrict__ Wout,
          const float* __restrict__ bout, const int*   __restrict__ seq,
          const int*   __restrict__ dep,  float* __restrict__ vbuf,
          unsigned*    __restrict__ flags, float* __restrict__ dout) {
    extern __shared__ float lds[];
    float* WoutL = lds;                 // 128*257
    float* hid   = WoutL + L_WOUT;      // 2*128
    float* g     = hid   + 256;         // 2*512 gate pre-acts; reused as cat[2][256]
    float* gin   = g     + 1024;        // 2*128
    float* qv    = gin   + 256;
    float* ug    = qv    + 256;
    float* sg    = ug    + 256;
    float* ctr   = sg    + 256;
    float* scor  = ctr   + 256;         // 2*32
    float* pmix  = scor  + 64;          // 16 rows * 128 (mix partials; reused as Wout partials)
    float* fxy   = pmix  + 2048;        // 2 parities * 8
    float* boutL = fxy   + 16;          // 128
    int*   depv  = (int*)(boutL + 128); // 2*25 (+pad)

    const int tid  = threadIdx.x;       // 0..1023
    const int blk  = blockIdx.x;
    const int lane = tid & 63;
    const int w    = tid >> 6;          // wave 0..15
    const int wj   = w >> 3;            // chain of this wave
    const int ww   = w & 7;             // wave-within-chain (8 per chain)

    // ---- persistent register weights: HALF a W_hh row per thread (64 VGPRs) ----
    const int o    = tid >> 1;          // row 0..511
    const int half = tid & 1;           // which 64-col half
    float4 wr[16];                      // MUST stay statically indexed (rule #20)
    {
        const float4* wp = (const float4*)(Whh + (size_t)o * Hc + half * 64);
        #pragma unroll
        for (int i = 0; i < 16; ++i) wr[i] = wp[i];
    }
    const float bihr = bih[o], bhhr = bhh[o];
    const float wih0 = Wih[o * 2 + 0], wih1 = Wih[o * 2 + 1];
    const int chunk = o >> 7;

    // stage W_out (stride-257) + b_out into LDS
    for (int i = tid; i < 128 * 256; i += 1024)
        WoutL[(i >> 8) * WSTRIDE + (i & 255)] = Wout[i];
    if (tid < 128) boutL[tid] = bout[tid];
    if (tid < 256) hid[tid] = 0.f;
    if (tid < 8) { int j = tid >> 2, c = tid & 3;
                   fxy[tid] = feat[((size_t)(blk * 2 + j) * Tc + 0) * 4 + c]; }
    const int s0 = max(seq[blk * 2 + 0], 1) - 1;
    const int s1 = max(seq[blk * 2 + 1], 1) - 1;
    __syncthreads();

    const float NEG_INF = -__builtin_inff();

    for (int t = 0; t < Tc; ++t) {
        const float* fx = fxy + (t & 1) * 8;

        // ---- P1: half-row gh dots (FULL unroll -> static wr index) ----
        float acc0j, acc1j;
        {
            const float4* hp0 = (const float4*)(hid + half * 64);
            const float4* hp1 = (const float4*)(hid + 128 + half * 64);
            float a0 = 0.f, a1 = 0.f, a2 = 0.f, a3 = 0.f;
            float b0 = 0.f, b1 = 0.f, b2 = 0.f, b3 = 0.f;
            #pragma unroll
            for (int i = 0; i < 16; ++i) {
                float4 w4 = wr[i];
                float4 h0 = hp0[i], h1 = hp1[i];
                a0 = fmaf(w4.x, h0.x, a0); a1 = fmaf(w4.y, h0.y, a1);
                a2 = fmaf(w4.z, h0.z, a2); a3 = fmaf(w4.w, h0.w, a3);
                b0 = fmaf(w4.x, h1.x, b0); b1 = fmaf(w4.y, h1.y, b1);
                b2 = fmaf(w4.z, h1.z, b2); b3 = fmaf(w4.w, h1.w, b3);
            }
            acc0j = (a0 + a1) + (a2 + a3);
            acc1j = (b0 + b1) + (b2 + b3);
        }
        acc0j += __shfl_xor(acc0j, 1, 64);
        acc1j += __shfl_xor(acc1j, 1, 64);
        if (half == 0) {
            float gi0 = fmaf(wih0, fx[0], wih1 * fx[1]);
            float gi1 = fmaf(wih0, fx[4], wih1 * fx[5]);
            float v0 = acc0j + bhhr + ((chunk == 2) ? 0.f : (gi0 + bihr));
            float v1 = acc1j + bhhr + ((chunk == 2) ? 0.f : (gi1 + bihr));
            g[o] = v0;
            g[512 + o] = v1;
            if (chunk == 2) { gin[o & 127] = gi0 + bihr; gin[128 + (o & 127)] = gi1 + bihr; }
        }
        if (tid < 50) {
            int j = (tid >= 25), k = tid - j * 25;
            depv[tid] = dep[(((size_t)(blk * 2 + j)) * Tc + t) * 25 + k];
        }
        if (tid >= 56 && tid < 64 && t + 1 < Tc) {
            int idx = tid - 56, j = idx >> 2, c = idx & 3;
            fxy[((t + 1) & 1) * 8 + idx] =
                feat[((size_t)(blk * 2 + j) * Tc + (t + 1)) * 4 + c];
        }
        __syncthreads();

        // ---- P2: gates (tid<256) + wave-parallel spin (1 dep per lane) ----
        if (tid < 256) {
            int j = tid >> 7, h = tid & 127;
            float gr = g[j * 512 + h],       gu = g[j * 512 + 128 + h];
            float gn = g[j * 512 + 256 + h], gs = g[j * 512 + 384 + h];
            float rr = fsig(gr), uu = fsig(gu), ss = fsig(gs);
            float nn = ftanh(gin[j * 128 + h] + rr * gn);
            qv[j * 128 + h] = nn; ug[j * 128 + h] = uu; sg[j * 128 + h] = ss;
            ctr[j * 128 + h] = 0.f;
        }
        {
            int e = (lane < 25) ? depv[wj * 25 + lane] : -1;
            bool pend = (e >= 0);
            if (pend && __hip_atomic_load(&flags[e], __ATOMIC_RELAXED,
                                          __HIP_MEMORY_SCOPE_AGENT) != 0u)
                pend = false;
            while (__any(pend)) {
                __builtin_amdgcn_s_sleep(1);
                if (pend && __hip_atomic_load(&flags[e], __ATOMIC_RELAXED,
                                              __HIP_MEMORY_SCOPE_AGENT) != 0u)
                    pend = false;
            }
            asm volatile("" ::: "memory");   // keep vbuf loads after the spin
        }
        __syncthreads();

        // ---- P4: gather (cached; flag-gated write-once lines) + scores ----
        const float q0 = qv[wj * 128 + 2 * lane];
        const float q1 = qv[wj * 128 + 2 * lane + 1];
        #pragma unroll
        for (int kk = 0; kk < 4; ++kk) {
            int k = ww + 8 * kk;
            if (k < 25) {
                int e = depv[wj * 25 + k];
                float sc;
                if (e >= 0) {
                    float2 v = *(const float2*)(vbuf + (size_t)e * Hc + 2 * lane);
                    float d = fmaf(v.x, q0, v.y * q1);
                    #pragma unroll
                    for (int m = 1; m < 64; m <<= 1) d += __shfl_xor(d, m, 64);
                    sc = (d == 0.f) ? NEG_INF : d;
                    if (k == 12) { ctr[wj * 128 + 2 * lane]     = v.x;
                                   ctr[wj * 128 + 2 * lane + 1] = v.y; }
                } else sc = NEG_INF;
                if (lane == 0) scor[wj * 32 + k] = sc;
            }
        }
        __syncthreads();

        // ---- P56: per-wave softmax + mix partials (vbuf re-read L1-hot) ----
        {
            int k2 = lane & 31;
            float v = (k2 < 25) ? scor[wj * 32 + k2] : NEG_INF;
            float m = v;
            #pragma unroll
            for (int mm = 1; mm < 32; mm <<= 1) m = fmaxf(m, __shfl_xor(m, mm, 64));
            float a = 0.f;
            if (m != NEG_INF) {
                float p = (v == NEG_INF) ? 0.f : fexp(v - m);
                float s = p;
                #pragma unroll
                for (int mm = 1; mm < 32; mm <<= 1) s += __shfl_xor(s, mm, 64);
                a = p / s;
            }
            float pm0 = 0.f, pm1 = 0.f;
            #pragma unroll
            for (int kk = 0; kk < 4; ++kk) {
                int k = ww + 8 * kk;
                if (k < 25) {
                    int e = depv[wj * 25 + k];
                    if (e >= 0) {
                        float ak = __shfl(a, k, 64);
                        float2 v = *(const float2*)(vbuf + (size_t)e * Hc + 2 * lane);
                        pm0 = fmaf(ak, v.x, pm0);
                        pm1 = fmaf(ak, v.y, pm1);
                    }
                }
            }
            *(float2*)&pmix[(wj * 8 + ww) * 128 + 2 * lane] = make_float2(pm0, pm1);
        }
        __syncthreads();

        // ---- P7a: cat = [mix, q] into g ----
        if (tid < 256) {
            int j = tid >> 7, h = tid & 127;
            float mix = 0.f;
            #pragma unroll
            for (int p = 0; p < 8; ++p) mix += pmix[(j * 8 + p) * 128 + h];
            g[j * 512 + h] = mix;
            g[j * 512 + 128 + h] = qv[j * 128 + h];
        }
        __syncthreads();

        // ---- P7b: W_out partial dots (8-way col split; scalar stride-257 reads) ----
        {
            int oo = tid & 127, rep = tid >> 7;     // rep: 32-col slice
            const float* wrow = WoutL + oo * WSTRIDE + rep * 32;
            const float* c0   = g + rep * 32;        // wave-uniform broadcast
            const float* c1   = g + 512 + rep * 32;
            float acc0 = 0.f, acc1 = 0.f;
            #pragma unroll
            for (int i = 0; i < 32; ++i) {
                float wv = wrow[i];
                acc0 = fmaf(wv, c0[i], acc0);
                acc1 = fmaf(wv, c1[i], acc1);
            }
            pmix[rep * 128 + oo]       = acc0;       // chain 0 partials: rows 0..7
            pmix[(8 + rep) * 128 + oo] = acc1;       // chain 1 partials: rows 8..15
        }
        __syncthreads();

        // ---- P7c: combine + epilogue + vbuf/dout stores ----
        if (tid < 256) {
            int j = tid >> 7, h = tid & 127;
            float tot = boutL[h];
            #pragma unroll
            for (int p = 0; p < 8; ++p) tot += pmix[(j * 8 + p) * 128 + h];
            float at = ftanh(tot);
            float n  = qv[j * 128 + h], uu = ug[j * 128 + h];
            float ss = sg[j * 128 + h], hv = hid[j * 128 + h];
            float curr = fmaf(ss, at, n);
            float outv = curr + uu * (hv - curr);
            hid[j * 128 + h] = outv;
            float upd = fmaf(ss, ctr[j * 128 + h], (1.f - ss) * outv);
            __hip_atomic_store(&vbuf[((size_t)(t * Bc + blk * 2 + j)) * Hc + h],
                               upd, __ATOMIC_RELAXED, __HIP_MEMORY_SCOPE_AGENT);
            int sj = (j == 0) ? s0 : s1;
            if (sj == t) dout[(size_t)(blk * 2 + j) * Hc + h] = outv;
        }
        __syncthreads();   // drains vmcnt(0): vbuf stores device-visible
        if (tid == 0 || tid == 128) {
            int j = tid >> 7;
            __hip_atomic_store(&flags[t * Bc + blk * 2 + j], 1u,
                               __ATOMIC_RELAXED, __HIP_MEMORY_SCOPE_AGENT);
        }
    }
}

// ---------------- host launch ----------------

extern "C" void kernel_launch(void* const* d_in, const int* in_sizes, int n_in,
                              void* d_out, int out_size, void* d_ws, size_t ws_size,
                              hipStream_t stream) {
    const float* feat = (const float*)d_in[0];
    const float* Wih  = (const float*)d_in[1];
    const float* bih  = (const float*)d_in[2];
    const float* Whh  = (const float*)d_in[3];
    const float* bhh  = (const float*)d_in[4];
    const float* Wout = (const float*)d_in[5];
    const float* bout = (const float*)d_in[6];
    const int*   seq  = (const int*)d_in[7];

    char* ws = (char*)d_ws;
    size_t off = 0;
    auto carve = [&](size_t bytes) { char* p = ws + off; off += (bytes + 511) & ~(size_t)511; return p; };
    float*    vbuf   = (float*)   carve((size_t)NEV * Hc * 4);
    int*      head   = (int*)     carve((size_t)NCELL * 4);
    int*      nxt    = (int*)     carve((size_t)NEV * 4);
    int*      cellxy = (int*)     carve((size_t)NEV * 4);
    int*      dep    = (int*)     carve((size_t)NEV * 25 * 4);
    unsigned* flags  = (unsigned*)carve((size_t)NEV * 4);

    hipMemsetAsync(head, 0xFF, (size_t)NCELL * 4, stream);
    hipMemsetAsync(flags, 0, (size_t)NEV * 4, stream);

    k_build<<<(NEV + 255) / 256, 256, 0, stream>>>(feat, head, nxt, cellxy);
    k_resolve<<<(NEV * 25 + 255) / 256, 256, 0, stream>>>(head, nxt, cellxy, dep);

    hipFuncSetAttribute((const void*)step_main,
                        hipFuncAttributeMaxDynamicSharedMemorySize, LDS_BYTES);
    step_main<<<256, 1024, LDS_BYTES, stream>>>(feat, Wih, bih, Whh, bhh, Wout, bout,
                                                seq, dep, vbuf, flags, (float*)d_out);
}